// Round 6
// baseline (166.928 us; speedup 1.0000x reference)
//
#include <hip/hip_runtime.h>
#include <math.h>

// NetVLAD: B=8, N=2048, D=128, K=64, fp32 in/out.
#define BB 8
#define NN 2048
#define DD 128
#define KK 64
#define PP 128           // blocks per batch for K1 (1024 blocks = 4/CU resident)
#define NPB (NN / PP)    // 16 descriptors per block

// ---------------------------------------------------------------------------
// Cross-lane reduction helpers (VALU DPP, not DS pipe).
// dpp_ctrl must be an integer-constant-expression -> template parameter.
// ---------------------------------------------------------------------------
template <int CTRL>
__device__ __forceinline__ float dppadd(float x) {
    return x + __int_as_float(__builtin_amdgcn_update_dpp(
        0, __float_as_int(x), CTRL, 0xF, 0xF, true));
}
__device__ __forceinline__ float row16sum(float x) {
    x = dppadd<0xB1>(x);   // quad_perm [1,0,3,2]: xor1 within quad
    x = dppadd<0x4E>(x);   // quad_perm [2,3,0,1]: xor2 within quad
    x = dppadd<0x141>(x);  // ROW_HALF_MIRROR: combine quads within 8
    x = dppadd<0x140>(x);  // ROW_MIRROR: combine 8-halves within 16
    return x;
}
__device__ __forceinline__ float sum32(float x) {  // 32-lane group sum
    x = row16sum(x);
    return x + __int_as_float(
        __builtin_amdgcn_ds_swizzle(__float_as_int(x), 0x401F));  // xor16
}
__device__ __forceinline__ float dot4(float4 a, float4 b) {
    return a.x*b.x + a.y*b.y + a.z*b.z + a.w*b.w;
}

// ---------------------------------------------------------------------------
// K1: fused normalize + assignment softmax + weighted accumulation.
// Round-5 lesson: the kernel is latency/barrier-bound (VALUBusy 18%, Occ 17%),
// so this round maximizes co-residency (PP=128 -> 4 blocks/CU) and cuts
// barriers to 4 per 8-descriptor chunk (was 6): one Phase B over all 8 rows,
// one rsum phase, one Phase C. e values live in eL (LDS) and are re-read in
// Phase C via broadcast float4 -> keeps VGPR ~90 for 4-block residency.
// Thread t: kq = t>>4 owns 4 k's (k = kq*4+kk); pr = t&15 owns d-chunks
// {pr*4..+3} and {64+pr*4..+3}; 16-lane DPP reductions for dots.
// NOTE: a = e*rsum is UNIFORM across the 16 pr lanes -> sA must NOT be
// cross-pr reduced in the epilogue (round-4 bug).
// ---------------------------------------------------------------------------
__global__ __launch_bounds__(256, 4) void netvlad_k1(
    const float* __restrict__ x, const float* __restrict__ cent,
    float* __restrict__ part_acc, float* __restrict__ part_sA)
{
    const int b    = blockIdx.x >> 7;    // / PP
    const int p    = blockIdx.x & 127;   // % PP
    const int t    = threadIdx.x;
    const int kq   = t >> 4;             // 0..15
    const int pr   = t & 15;             // 0..15
    const int wave = t >> 6;
    const int lane = t & 63;
    const int half = (t >> 5) & 1;
    const int hl   = t & 31;

    __shared__ float4 xn4[8][32];            // 4 KB: normalized descriptors
    __shared__ float  eL[8][KK];             // 2 KB: exp values, 8 rows
    __shared__ __align__(32) float rsum[8];  // reciprocal softmax denominators

    // Centroid fragments in registers + per-k ||c||^2 (full 128-d via DPP).
    float4 c0[4], c1[4];
    float cn2[4];
    #pragma unroll
    for (int kk = 0; kk < 4; ++kk) {
        const int k = kq * 4 + kk;
        c0[kk] = *(const float4*)(cent + k * DD + pr * 4);
        c1[kk] = *(const float4*)(cent + k * DD + 64 + pr * 4);
        cn2[kk] = row16sum(dot4(c0[kk], c0[kk]) + dot4(c1[kk], c1[kk]));
    }

    float4 acc0[4], acc1[4];
    float sA[4];
    #pragma unroll
    for (int kk = 0; kk < 4; ++kk) {
        acc0[kk] = make_float4(0.f, 0.f, 0.f, 0.f);
        acc1[kk] = make_float4(0.f, 0.f, 0.f, 0.f);
        sA[kk] = 0.f;
    }

    const float* xb = x + ((size_t)b * NN + (size_t)p * NPB) * DD;

    for (int outer = 0; outer < NPB / 8; ++outer) {   // 2 iterations
        __syncthreads();  // xn4/eL/rsum safe to overwrite (prev Phase C done)

        // ---- Phase A: load + L2-normalize 8 descriptors (half-wave each)
        {
            const int r = (wave << 1) | half;   // row 0..7
            const float* xp = xb + (size_t)(outer * 8 + r) * DD + hl * 4;
            float4 v = *(const float4*)xp;
            float ss = sum32(v.x*v.x + v.y*v.y + v.z*v.z + v.w*v.w);
            const float rn = 1.0f / fmaxf(sqrtf(ss), 1e-12f);
            xn4[r][hl] = make_float4(v.x*rn, v.y*rn, v.z*rn, v.w*rn);
        }
        __syncthreads();

        // ---- Phase B: dots + exp for ALL 8 rows. assign ∝ exp(||c||²-2xn·c)
        #pragma unroll
        for (int i = 0; i < 8; ++i) {
            const float4 u0 = xn4[i][pr];
            const float4 u1 = xn4[i][16 + pr];
            float ev[4];
            #pragma unroll
            for (int kk = 0; kk < 4; ++kk) {
                float S = dot4(u0, c0[kk]) + dot4(u1, c1[kk]);
                S = row16sum(S);
                ev[kk] = __expf(cn2[kk] - 2.0f * S);
            }
            if (pr == 0)
                *(float4*)(&eL[i][kq * 4]) =
                    make_float4(ev[0], ev[1], ev[2], ev[3]);
        }
        __syncthreads();

        // ---- softmax denominators: wave w reduces rows w and w+4
        #pragma unroll
        for (int rep = 0; rep < 2; ++rep) {
            const int row = wave + rep * 4;
            const float2 ev = *(const float2*)(&eL[row][(lane & 31) * 2]);
            const float s = sum32(ev.x + ev.y);
            if (lane == 0) rsum[row] = 1.0f / s;
        }
        __syncthreads();

        // ---- Phase C: accumulate assign * xn into register tile
        float rsv[8];
        *(float4*)(&rsv[0]) = *(const float4*)(&rsum[0]);
        *(float4*)(&rsv[4]) = *(const float4*)(&rsum[4]);
        #pragma unroll
        for (int i = 0; i < 8; ++i) {
            const float4 u0 = xn4[i][pr];
            const float4 u1 = xn4[i][16 + pr];
            const float4 ef = *(const float4*)(&eL[i][kq * 4]);  // broadcast
            const float ri = rsv[i];
            #pragma unroll
            for (int kk = 0; kk < 4; ++kk) {
                const float a = (&ef.x)[kk] * ri;
                sA[kk] += a;
                acc0[kk].x += a*u0.x; acc0[kk].y += a*u0.y;
                acc0[kk].z += a*u0.z; acc0[kk].w += a*u0.w;
                acc1[kk].x += a*u1.x; acc1[kk].y += a*u1.y;
                acc1[kk].z += a*u1.z; acc1[kk].w += a*u1.w;
            }
        }
    }

    // ---- epilogue: sA already complete in every pr lane (a uniform across
    // pr) — write pr==0's copy, NO cross-pr reduction (round-4 bug).
    if (pr == 0) {
        #pragma unroll
        for (int kk = 0; kk < 4; ++kk)   // layout [b][k][p] for coalesced k2
            part_sA[((size_t)b * KK + kq * 4 + kk) * PP + p] = sA[kk];
    }
    const size_t base = (size_t)(b * PP + p) * KK * DD;
    #pragma unroll
    for (int kk = 0; kk < 4; ++kk) {
        const int k = kq * 4 + kk;
        *(float4*)(part_acc + base + k * DD + pr * 4)      = acc0[kk];
        *(float4*)(part_acc + base + k * DD + 64 + pr * 4) = acc1[kk];
    }
}

// ---------------------------------------------------------------------------
// K2: reduce 128 partials per (b,k), subtract c*sumA, intra-normalize, apply
// global scale. Every intra-normalized row has sumsq == 1 (to ~1e-7), so the
// global norm is sqrt(K)=8 exactly — fold 0.125 here, no third pass.
// Grid: BB*KK = 512 blocks of 128 threads.
// ---------------------------------------------------------------------------
__global__ __launch_bounds__(128) void netvlad_k2(
    const float* __restrict__ cent, const float* __restrict__ part_acc,
    const float* __restrict__ part_sA, float* __restrict__ out)
{
    const int b  = blockIdx.x >> 6;
    const int k  = blockIdx.x & 63;
    const int t  = threadIdx.x;
    const int d4 = t & 31;
    const int ps = t >> 5;

    __shared__ float sAL[2];
    {
        float sA = part_sA[((size_t)b * KK + k) * PP + t];  // coalesced, 128 p
        #pragma unroll
        for (int m = 1; m < 64; m <<= 1) sA += __shfl_xor(sA, m);
        if ((t & 63) == 0) sAL[t >> 6] = sA;
    }

    // each thread sums 32 p's of its float4 column
    float4 acc = make_float4(0.f, 0.f, 0.f, 0.f);
    const float* basep = part_acc + ((size_t)(b * PP) * KK + k) * DD + d4 * 4;
    #pragma unroll 8
    for (int pp = 0; pp < 32; ++pp) {
        const float4 v = *(const float4*)(basep + (size_t)(ps * 32 + pp) * KK * DD);
        acc.x += v.x; acc.y += v.y; acc.z += v.z; acc.w += v.w;
    }

    __shared__ float4 red[4][32];
    red[ps][d4] = acc;
    __syncthreads();
    const float sAt = sAL[0] + sAL[1];

    if (t < 32) {
        float4 v = red[0][t];
        #pragma unroll
        for (int s = 1; s < 4; ++s) {
            v.x += red[s][t].x; v.y += red[s][t].y;
            v.z += red[s][t].z; v.w += red[s][t].w;
        }
        const float4 c = *(const float4*)(cent + k * DD + t * 4);
        v.x -= c.x * sAt; v.y -= c.y * sAt; v.z -= c.z * sAt; v.w -= c.w * sAt;

        float ss = v.x*v.x + v.y*v.y + v.z*v.z + v.w*v.w;
        #pragma unroll
        for (int m = 1; m < 32; m <<= 1) ss += __shfl_xor(ss, m);
        const float rn = 0.125f / fmaxf(sqrtf(ss), 1e-12f);
        v.x *= rn; v.y *= rn; v.z *= rn; v.w *= rn;
        *(float4*)(out + ((size_t)b * KK + k) * DD + t * 4) = v;
    }
}

extern "C" void kernel_launch(void* const* d_in, const int* in_sizes, int n_in,
                              void* d_out, int out_size, void* d_ws, size_t ws_size,
                              hipStream_t stream) {
    const float* x    = (const float*)d_in[0];   // [8, 2048, 128] fp32
    const float* cent = (const float*)d_in[1];   // [64, 128] fp32
    float* out = (float*)d_out;                  // [8, 8192] fp32

    char* ws = (char*)d_ws;
    float* part_sA  = (float*)ws;                 // 8*64*128 fp32 = 256 KB
    float* part_acc = (float*)(ws + (1 << 18));   // 8*128*64*128 fp32 = 32 MB

    netvlad_k1<<<dim3(BB * PP), dim3(256), 0, stream>>>(x, cent, part_acc, part_sA);
    netvlad_k2<<<dim3(BB * KK), dim3(128), 0, stream>>>(cent, part_acc, part_sA, out);
}

// Round 7
// 99.100 us; speedup vs baseline: 1.6844x; 1.6844x over previous
//
#include <hip/hip_runtime.h>
#include <math.h>

// NetVLAD: B=8, N=2048, D=128, K=64, fp32 in/out.
#define BB 8
#define NN 2048
#define DD 128
#define KK 64
#define PP 32            // partial-writing blocks per batch (8 MB partials)
#define QD 4             // quads (independent 256-thread pipelines) per block

// ---------------------------------------------------------------------------
// Cross-lane reduction helpers (VALU DPP, not DS pipe).
// ---------------------------------------------------------------------------
template <int CTRL>
__device__ __forceinline__ float dppadd(float x) {
    return x + __int_as_float(__builtin_amdgcn_update_dpp(
        0, __float_as_int(x), CTRL, 0xF, 0xF, true));
}
__device__ __forceinline__ float row16sum(float x) {
    x = dppadd<0xB1>(x);   // quad_perm [1,0,3,2]: xor1
    x = dppadd<0x4E>(x);   // quad_perm [2,3,0,1]: xor2
    x = dppadd<0x141>(x);  // ROW_HALF_MIRROR: xor4
    x = dppadd<0x140>(x);  // ROW_MIRROR: xor8
    return x;
}
__device__ __forceinline__ float sum32(float x) {
    x = row16sum(x);
    return x + __int_as_float(
        __builtin_amdgcn_ds_swizzle(__float_as_int(x), 0x401F));  // xor16
}
__device__ __forceinline__ float dot4(float4 a, float4 b) {
    return a.x*b.x + a.y*b.y + a.z*b.z + a.w*b.w;
}

// ---------------------------------------------------------------------------
// K1: fused normalize + softmax-assign + weighted accumulation.
// Grid: BB*PP = 256 blocks x 1024 threads (16 waves/CU).
// Quad q = threads [256q,256q+256) handles descriptors [p*64+q*16, +16)
// with the 4-barrier pipeline (quad-private LDS); the epilogue merges the
// 4 quads' register tiles in LDS over 4 rounds, then ONE coalesced 32 KB
// global write per block. Partials: 256 blocks x 32 KB = 8 MB total —
// the round-1 "clean" traffic regime, now at 4x the waves/CU.
// Within a quad: kq = tq>>4 owns 4 k's; pr = tq&15 owns d-chunks
// {pr*4..+3} and {64+pr*4..+3}; 16-lane DPP reductions for dots.
// NOTE: a = e*rsum is UNIFORM across pr lanes -> sA is already the full
// per-k sum in each lane; never cross-pr reduce it (round-4 bug).
// ---------------------------------------------------------------------------
#define TSTRIDE 33   // tile row stride in float4 (pad kills 8-way bank alias)

__global__ __launch_bounds__(1024, 4) void netvlad_k1(
    const float* __restrict__ x, const float* __restrict__ cent,
    float* __restrict__ part_acc, float* __restrict__ part_sA)
{
    const int b    = blockIdx.x >> 5;    // / PP
    const int p    = blockIdx.x & 31;    // % PP
    const int t    = threadIdx.x;        // 0..1023
    const int quad = t >> 8;             // 0..3
    const int tq   = t & 255;            // thread-in-quad
    const int kq   = tq >> 4;            // 0..15
    const int pr   = tq & 15;            // 0..15
    const int wq   = (tq >> 6);          // wave-in-quad 0..3
    const int lane = t & 63;
    const int half = (tq >> 5) & 1;
    const int hl   = tq & 31;

    __shared__ float4 xn4[QD][8][32];            // 16 KB: normalized rows
    __shared__ float  eL[QD][8][KK];             //  8 KB: exp values
    __shared__ __align__(32) float rsum[QD][8];  // softmax reciprocals
    __shared__ float4 tile[KK * TSTRIDE];        // 33 KB: merged block tile
    __shared__ float  sAtile[KK];

    // Centroid fragments in registers + per-k ||c||^2 (128-d via DPP).
    float4 c0[4], c1[4];
    float cn2[4];
    #pragma unroll
    for (int kk = 0; kk < 4; ++kk) {
        const int k = kq * 4 + kk;
        c0[kk] = *(const float4*)(cent + k * DD + pr * 4);
        c1[kk] = *(const float4*)(cent + k * DD + 64 + pr * 4);
        cn2[kk] = row16sum(dot4(c0[kk], c0[kk]) + dot4(c1[kk], c1[kk]));
    }

    float4 acc0[4], acc1[4];
    float sA[4];
    #pragma unroll
    for (int kk = 0; kk < 4; ++kk) {
        acc0[kk] = make_float4(0.f, 0.f, 0.f, 0.f);
        acc1[kk] = make_float4(0.f, 0.f, 0.f, 0.f);
        sA[kk] = 0.f;
    }

    const float* xb = x + ((size_t)b * NN + (size_t)p * 64 + quad * 16) * DD;

    for (int outer = 0; outer < 2; ++outer) {
        __syncthreads();  // quad-private LDS safe to overwrite

        // ---- Phase A: load + L2-normalize 8 rows (one per half-wave)
        {
            const int r = (wq << 1) | half;   // row 0..7
            const float* xp = xb + (size_t)(outer * 8 + r) * DD + hl * 4;
            float4 v = *(const float4*)xp;
            float ss = sum32(v.x*v.x + v.y*v.y + v.z*v.z + v.w*v.w);
            const float rn = 1.0f / fmaxf(sqrtf(ss), 1e-12f);
            xn4[quad][r][hl] = make_float4(v.x*rn, v.y*rn, v.z*rn, v.w*rn);
        }
        __syncthreads();

        // ---- Phase B: dots + exp, all 8 rows. assign ∝ exp(||c||²-2xn·c)
        #pragma unroll
        for (int i = 0; i < 8; ++i) {
            const float4 u0 = xn4[quad][i][pr];
            const float4 u1 = xn4[quad][i][16 + pr];
            float ev[4];
            #pragma unroll
            for (int kk = 0; kk < 4; ++kk) {
                float S = dot4(u0, c0[kk]) + dot4(u1, c1[kk]);
                S = row16sum(S);
                ev[kk] = __expf(cn2[kk] - 2.0f * S);
            }
            if (pr == 0)
                *(float4*)(&eL[quad][i][kq * 4]) =
                    make_float4(ev[0], ev[1], ev[2], ev[3]);
        }
        __syncthreads();

        // ---- softmax denominators: wave (quad,wq) reduces rows wq, wq+4.
        // All 64 lanes read the same 32 float2's -> both 32-halves hold the
        // full row sum after sum32.
        #pragma unroll
        for (int rep = 0; rep < 2; ++rep) {
            const int row = wq + rep * 4;
            const float2 ev = *(const float2*)(&eL[quad][row][(lane & 31) * 2]);
            const float s = sum32(ev.x + ev.y);
            if (lane == 0) rsum[quad][row] = 1.0f / s;
        }
        __syncthreads();

        // ---- Phase C: accumulate assign * xn into register tile
        float rsv[8];
        *(float4*)(&rsv[0]) = *(const float4*)(&rsum[quad][0]);
        *(float4*)(&rsv[4]) = *(const float4*)(&rsum[quad][4]);
        #pragma unroll
        for (int i = 0; i < 8; ++i) {
            const float4 u0 = xn4[quad][i][pr];
            const float4 u1 = xn4[quad][i][16 + pr];
            const float4 ef = *(const float4*)(&eL[quad][i][kq * 4]);
            const float ri = rsv[i];
            #pragma unroll
            for (int kk = 0; kk < 4; ++kk) {
                const float a = (&ef.x)[kk] * ri;
                sA[kk] += a;
                acc0[kk].x += a*u0.x; acc0[kk].y += a*u0.y;
                acc0[kk].z += a*u0.z; acc0[kk].w += a*u0.w;
                acc1[kk].x += a*u1.x; acc1[kk].y += a*u1.y;
                acc1[kk].z += a*u1.z; acc1[kk].w += a*u1.w;
            }
        }
    }

    // ---- Epilogue: merge the 4 quads' tiles in LDS (4 rounds), then one
    // coalesced global write for the whole block.
    #pragma unroll
    for (int r = 0; r < QD; ++r) {
        __syncthreads();
        if (quad == r) {
            #pragma unroll
            for (int kk = 0; kk < 4; ++kk) {
                const int k = kq * 4 + kk;
                float4* t0 = &tile[k * TSTRIDE + pr];
                float4* t1 = &tile[k * TSTRIDE + 16 + pr];
                if (r == 0) {
                    *t0 = acc0[kk];
                    *t1 = acc1[kk];
                    if (pr == 0) sAtile[k] = sA[kk];
                } else {
                    float4 v0 = *t0, v1 = *t1;
                    v0.x += acc0[kk].x; v0.y += acc0[kk].y;
                    v0.z += acc0[kk].z; v0.w += acc0[kk].w;
                    v1.x += acc1[kk].x; v1.y += acc1[kk].y;
                    v1.z += acc1[kk].z; v1.w += acc1[kk].w;
                    *t0 = v0; *t1 = v1;
                    if (pr == 0) sAtile[k] += sA[kk];
                }
            }
        }
    }
    __syncthreads();

    // coalesced write: 2048 float4 by 1024 threads (2 each)
    float4* dst = (float4*)(part_acc + (size_t)(b * PP + p) * KK * DD);
    {
        const int f0 = t;            // float4 index in [0,2048)
        const int f1 = t + 1024;
        dst[f0] = tile[(f0 >> 5) * TSTRIDE + (f0 & 31)];
        dst[f1] = tile[(f1 >> 5) * TSTRIDE + (f1 & 31)];
    }
    if (t < KK)   // layout [b][k][p] for coalesced k2 read
        part_sA[((size_t)b * KK + t) * PP + p] = sAtile[t];
}

// ---------------------------------------------------------------------------
// K2: reduce 32 partials per (b,k), subtract c*sumA, intra-normalize, apply
// global scale. Every intra-normalized row has sumsq == 1 (to ~1e-7), so the
// global norm is sqrt(K)=8 exactly — fold 0.125, no third pass.
// Grid: BB*KK = 512 blocks of 128 threads. Thread t: d4=t&31 (float4 col),
// ps=t>>5 (slice of 8 partials).
// ---------------------------------------------------------------------------
__global__ __launch_bounds__(128) void netvlad_k2(
    const float* __restrict__ cent, const float* __restrict__ part_acc,
    const float* __restrict__ part_sA, float* __restrict__ out)
{
    const int b  = blockIdx.x >> 6;
    const int k  = blockIdx.x & 63;
    const int t  = threadIdx.x;
    const int d4 = t & 31;
    const int ps = t >> 5;

    __shared__ float sAL;
    if (t < 32) {
        float sA = part_sA[((size_t)b * KK + k) * PP + t];  // coalesced
        #pragma unroll
        for (int m = 1; m < 32; m <<= 1) sA += __shfl_xor(sA, m);
        if (t == 0) sAL = sA;
    }

    // each thread sums 8 p's of its float4 column
    float4 acc = make_float4(0.f, 0.f, 0.f, 0.f);
    const float* basep = part_acc +
        ((size_t)(b * PP + ps * 8) * KK + k) * DD + d4 * 4;
    #pragma unroll
    for (int pp = 0; pp < 8; ++pp) {
        const float4 v = *(const float4*)(basep + (size_t)pp * KK * DD);
        acc.x += v.x; acc.y += v.y; acc.z += v.z; acc.w += v.w;
    }

    __shared__ float4 red[4][32];
    red[ps][d4] = acc;
    __syncthreads();
    const float sAt = sAL;

    if (t < 32) {
        float4 v = red[0][t];
        #pragma unroll
        for (int s = 1; s < 4; ++s) {
            v.x += red[s][t].x; v.y += red[s][t].y;
            v.z += red[s][t].z; v.w += red[s][t].w;
        }
        const float4 c = *(const float4*)(cent + k * DD + t * 4);
        v.x -= c.x * sAt; v.y -= c.y * sAt; v.z -= c.z * sAt; v.w -= c.w * sAt;

        float ss = v.x*v.x + v.y*v.y + v.z*v.z + v.w*v.w;
        #pragma unroll
        for (int m = 1; m < 32; m <<= 1) ss += __shfl_xor(ss, m);
        const float rn = 0.125f / fmaxf(sqrtf(ss), 1e-12f);
        v.x *= rn; v.y *= rn; v.z *= rn; v.w *= rn;
        *(float4*)(out + ((size_t)b * KK + k) * DD + t * 4) = v;
    }
}

extern "C" void kernel_launch(void* const* d_in, const int* in_sizes, int n_in,
                              void* d_out, int out_size, void* d_ws, size_t ws_size,
                              hipStream_t stream) {
    const float* x    = (const float*)d_in[0];   // [8, 2048, 128] fp32
    const float* cent = (const float*)d_in[1];   // [64, 128] fp32
    float* out = (float*)d_out;                  // [8, 8192] fp32

    char* ws = (char*)d_ws;
    float* part_sA  = (float*)ws;                 // 8*64*32 fp32 = 64 KB
    float* part_acc = (float*)(ws + (1 << 17));   // 8*32*64*128 fp32 = 8 MB

    netvlad_k1<<<dim3(BB * PP), dim3(1024), 0, stream>>>(x, cent, part_acc, part_sA);
    netvlad_k2<<<dim3(BB * KK), dim3(128), 0, stream>>>(cent, part_acc, part_sA, out);
}